// Round 5
// baseline (145.473 us; speedup 1.0000x reference)
//
#include <hip/hip_runtime.h>

// ---------------------------------------------------------------------------
// SocialPooling: out = relu(pool(h, pos) @ W + b).  M=B=4096, K=4096, N=1024.
// R14: FUSED pooling+GEMM.  pooled (32 MB intermediate) is never materialized:
// each GEMM block owns 128 rows = 2 whole sequences and builds its A-tile
// (128 persons x 2 cells x 64 dims) in LDS per K-step from h (32 KB f32,
// staged once, XOR-swizzled) + neighbor bitmasks (2 MB ws, tiny prep).
//  - removes: pool prep kernel, pooled HBM write+read, A-side global staging.
//  - numerics identical to R9-R13 path (f32 sums -> one bf16 round).
//  - sync: pure __syncthreads (2/step), single As buffer, double Bs buffer,
//    Bs prefetched one tile ahead (issued in build phase, lands under MFMA).
//  - MFMA phase + swizzle + 2m x 2n x 2k wave split + K-half LDS reduction
//    epilogue carried verbatim from R13 (numerically verified, passed).
//  - ws: masks 2 MB + Wt 8 MB (was 40 MB).
// prep2: W cast/transpose (1024 blocks, verbatim) + mask build (64 blocks).
// ---------------------------------------------------------------------------

#define BM 128
#define BN 128
#define BK 128   // shorts (bf16) per K-block = 2 grid cells

typedef short short8 __attribute__((ext_vector_type(8)));
typedef short short4v __attribute__((ext_vector_type(4)));
typedef float floatx16 __attribute__((ext_vector_type(16)));
typedef unsigned long long u64;

__device__ inline short f2bf(float x) {
    union { float f; unsigned u; } v; v.f = x;
    unsigned r = v.u + 0x7fffu + ((v.u >> 16) & 1u);   // round-to-nearest-even
    return (short)(r >> 16);
}

__device__ inline void gload_lds16(const void* g, void* l) {
    __builtin_amdgcn_global_load_lds(
        (const __attribute__((address_space(1))) void*)g,
        (__attribute__((address_space(3))) void*)l,
        16, 0, 0);
}

// ---------------------------------------------------------------------------
// Kernel 1: prep2 = W transpose/cast (blocks 0..1023) + neighbor-mask build
// (blocks 1024..1087, one per sequence).
// masks[p][c] = bitmask over the 64 sequence-mates j of person p that fall in
// grid cell c of p's window (strict-inequality window, j != p) — exactly the
// verified pool-kernel cell logic.
// ---------------------------------------------------------------------------
__global__ __launch_bounds__(256) void prep2_kernel(
    const float* __restrict__ pos,   // (B, 2)
    u64* __restrict__ masks,         // (B, 64)
    const float* __restrict__ W,     // (K, N) f32
    short* __restrict__ Wt,          // (N, K) bf16
    int K, int N, int castBlocks)
{
    __shared__ __align__(16) unsigned char sh[33280];
    const int tid = threadIdx.x;

    if ((int)blockIdx.x < castBlocks) {
        // ----- W (K x N f32) -> Wt (N x K bf16), 64x64 tiles (verbatim) -----
        float* t = (float*)sh;                 // [64][65]
        const int bid = blockIdx.x;
        const int k0 = (bid & 63) * 64;
        const int n0 = (bid >> 6) * 64;

        const int r  = tid >> 4;               // 0..15
        const int cq = (tid & 15) * 4;
        #pragma unroll
        for (int i2 = 0; i2 < 4; ++i2) {
            const int row = r + i2 * 16;
            float4 v = *(const float4*)&W[(size_t)(k0 + row) * N + n0 + cq];
            t[row * 65 + cq + 0] = v.x; t[row * 65 + cq + 1] = v.y;
            t[row * 65 + cq + 2] = v.z; t[row * 65 + cq + 3] = v.w;
        }
        __syncthreads();
        const int nl = tid >> 4;
        const int kq = (tid & 15) * 4;
        #pragma unroll
        for (int i2 = 0; i2 < 4; ++i2) {
            const int n = nl + i2 * 16;
            short4v o;
            o.x = f2bf(t[(kq + 0) * 65 + n]); o.y = f2bf(t[(kq + 1) * 65 + n]);
            o.z = f2bf(t[(kq + 2) * 65 + n]); o.w = f2bf(t[(kq + 3) * 65 + n]);
            *(short4v*)&Wt[(size_t)(n0 + n) * K + k0 + kq] = o;
        }
    } else {
        // ----- neighbor masks for one sequence -----
        float* px = (float*)sh;                 // 64
        float* py = px + 64;                    // 64
        u64*   lm = (u64*)(sh + 512);           // 64 persons x 64 cells = 32 KB

        const int s = blockIdx.x - castBlocks;
        const size_t base = (size_t)s * 64;

        if (tid < 64) {
            float2 p = ((const float2*)pos)[base + tid];
            px[tid] = p.x; py[tid] = p.y;
        }
        for (int k = tid; k < 4096; k += 256) lm[k] = 0ull;
        __syncthreads();

        const int i  = tid >> 2;                // person 0..63
        const int j0 = (tid & 3) * 16;          // mate group
        const float tlx = px[i] - 1.0f;
        const float tly = py[i] + 1.0f;
        const float brx = px[i] + 1.0f;
        const float bry = py[i] - 1.0f;
        #pragma unroll
        for (int jj = 0; jj < 16; ++jj) {
            const int j = j0 + jj;
            const float ox = px[j], oy = py[j];
            if (ox < brx && ox > tlx && oy < tly && oy > bry && j != i) {
                int cx = (int)floorf((ox - tlx) * 4.0f);
                int cy = (int)floorf((tly - oy) * 4.0f);
                atomicOr(&lm[i * 64 + cx + cy * 8], 1ull << j);
            }
        }
        __syncthreads();

        ulonglong2*       dst = (ulonglong2*)(masks + base * 64);
        const ulonglong2* src = (const ulonglong2*)lm;
        for (int k = tid; k < 2048; k += 256) dst[k] = src[k];
    }
}

// ---------------------------------------------------------------------------
// Kernel 2: fused pool+GEMM.  C = relu(pool(h) @ Wt^T + bias).
// 128x128 tile, 8 waves (wr, wn, kh), wave tile 64x64 over a K-half.
// Per K-step i:  MFMA(i) [As, Bs[i&1]] ; sync ;
//                issue Bs(i+1) -> buf[(i+1)&1] ; build As(i+1) from h+masks ;
//                sync (drains Bs(i+1), As writes visible).
// h: [128][64] f32 LDS, granule-XOR-swizzled via pre-swizzled global source.
// ---------------------------------------------------------------------------
__global__ __launch_bounds__(512) void fused_pool_gemm(
    const float* __restrict__ h,      // (B, 64) f32
    const u64* __restrict__ masks,    // (B, 64)
    const short* __restrict__ Bt,     // (N, K) bf16
    const float* __restrict__ bias,   // (N,)
    float* __restrict__ out,          // (M, N)
    int M, int N, int K)
{
    __shared__ __align__(16) short As[BM * BK];      // 32 KB (single buffer)
    __shared__ __align__(16) short Bs[2][BN * BK];   // 2 x 32 KB
    __shared__ __align__(16) float hs[BM * 64];      // 32 KB  -> 128 KB total

    const int tid  = threadIdx.x;
    const int lane = tid & 63;
    const int wave = tid >> 6;         // 0..7
    const int kh = wave & 1;           // K-half
    const int wn = (wave >> 1) & 1;    // n-half
    const int wr = wave >> 2;          // m-half
    const int nl = lane & 31;          // MFMA row/col within 32
    const int hl = lane >> 5;          // K-half within granule pair
    const int ml = lane & 15;          // swizzle key (= row&15)

    // XCD m-clustered mapping (dispatch: block b -> XCD b%8); grid 256.
    const int b  = blockIdx.x;
    const int ib = b >> 3;                         // 0..31
    const int m0 = ((b & 7) * 4 + (ib >> 3)) * BM; // m-tile 0..31
    const int n0 = (ib & 7) * BN;                  // n-tile 0..7

    const int r4   = lane >> 4;        // row within 4-row staging group
    const int slot = lane & 15;        // 16B-granule slot within row

    // ---- staging pointers (pre-swizzled global sources, linear LDS) ----
    const short* bg[4];
    const float* hg[4];
    #pragma unroll
    for (int c = 0; c < 4; ++c) {
        const int gi = c * 8 + wave;           // 0..31
        const int rl = gi * 4 + r4;            // 0..127
        bg[c] = Bt + (size_t)(n0 + rl) * K + (slot ^ (rl & 15)) * 8;
        hg[c] = h  + (size_t)(m0 + rl) * 64 + (slot ^ (rl & 15)) * 4;
    }

    // ---- build-thread mapping: t -> (row, cell, dim-half) ----
    const int br = tid >> 2;           // row 0..127
    const int bc = (tid >> 1) & 1;     // cell within K-step: 0/1
    const int bq = tid & 1;            // dim half: dims 32*bq .. +32
    const int hb = br & 64;            // sequence base row within hs
    const u64* mrow = masks + (size_t)(m0 + br) * 64 + bc;  // step k: mrow[2k]

    floatx16 acc[4];                   // [mi*2+ni]
    #pragma unroll
    for (int i = 0; i < 4; ++i)
        #pragma unroll
        for (int r = 0; r < 16; ++r) acc[i][r] = 0.f;

    // ---- prologue: mask regs + h + Bs(0) ----
    u64 m_cur = mrow[0];               // for build As(0)
    u64 mA    = mrow[2];               // for build As(1) in phase 0
    #pragma unroll
    for (int c = 0; c < 4; ++c) gload_lds16(hg[c], &hs[(c * 8 + wave) * 256]);
    #pragma unroll
    for (int c = 0; c < 4; ++c) { gload_lds16(bg[c], &Bs[0][(c * 8 + wave) * 512]); bg[c] += BK; }
    __syncthreads();                   // h + Bs(0) landed (all waves)

    // ---- build As(0) ----
    {
        float4 a0{0,0,0,0}, a1{0,0,0,0}, a2{0,0,0,0}, a3{0,0,0,0},
               a4{0,0,0,0}, a5{0,0,0,0}, a6{0,0,0,0}, a7{0,0,0,0};
        u64 m = m_cur;
        while (m) {
            const int j = __builtin_ctzll(m); m &= m - 1;
            const float* hr = &hs[(hb + j) << 6];
            const int key = (hb + j) & 15;
            a0 += *(const float4*)&hr[(((bq * 8 + 0) ^ key) << 2)];
            a1 += *(const float4*)&hr[(((bq * 8 + 1) ^ key) << 2)];
            a2 += *(const float4*)&hr[(((bq * 8 + 2) ^ key) << 2)];
            a3 += *(const float4*)&hr[(((bq * 8 + 3) ^ key) << 2)];
            a4 += *(const float4*)&hr[(((bq * 8 + 4) ^ key) << 2)];
            a5 += *(const float4*)&hr[(((bq * 8 + 5) ^ key) << 2)];
            a6 += *(const float4*)&hr[(((bq * 8 + 6) ^ key) << 2)];
            a7 += *(const float4*)&hr[(((bq * 8 + 7) ^ key) << 2)];
        }
        const int gbase = bc * 8 + bq * 4;
        short8 o;
        o[0]=f2bf(a0.x); o[1]=f2bf(a0.y); o[2]=f2bf(a0.z); o[3]=f2bf(a0.w);
        o[4]=f2bf(a1.x); o[5]=f2bf(a1.y); o[6]=f2bf(a1.z); o[7]=f2bf(a1.w);
        *(short8*)&As[(br << 7) + (((gbase + 0) ^ (br & 15)) << 3)] = o;
        o[0]=f2bf(a2.x); o[1]=f2bf(a2.y); o[2]=f2bf(a2.z); o[3]=f2bf(a2.w);
        o[4]=f2bf(a3.x); o[5]=f2bf(a3.y); o[6]=f2bf(a3.z); o[7]=f2bf(a3.w);
        *(short8*)&As[(br << 7) + (((gbase + 1) ^ (br & 15)) << 3)] = o;
        o[0]=f2bf(a4.x); o[1]=f2bf(a4.y); o[2]=f2bf(a4.z); o[3]=f2bf(a4.w);
        o[4]=f2bf(a5.x); o[5]=f2bf(a5.y); o[6]=f2bf(a5.z); o[7]=f2bf(a5.w);
        *(short8*)&As[(br << 7) + (((gbase + 2) ^ (br & 15)) << 3)] = o;
        o[0]=f2bf(a6.x); o[1]=f2bf(a6.y); o[2]=f2bf(a6.z); o[3]=f2bf(a6.w);
        o[4]=f2bf(a7.x); o[5]=f2bf(a7.y); o[6]=f2bf(a7.z); o[7]=f2bf(a7.w);
        *(short8*)&As[(br << 7) + (((gbase + 3) ^ (br & 15)) << 3)] = o;
    }
    __syncthreads();                   // As(0) visible

    const int NT = K / BK;             // 32
    for (int i = 0; i < NT; ++i) {
        const int cur = i & 1;
        // prefetch mask for build of step i+2 (used next phase)
        u64 mB = (i + 2 < NT) ? mrow[(size_t)(i + 2) * 2] : 0ull;

        __builtin_amdgcn_s_setprio(1);
        #pragma unroll
        for (int t = 0; t < 4; ++t) {              // 4 x K=16 steps (K-half)
            const int g  = kh * 8 + 2 * t + hl;    // granule 0..15
            const int go = (g ^ ml) * 8;
            short8 a0 = *(const short8*)&As[(wr * 64 +      nl) * BK + go];
            short8 a1 = *(const short8*)&As[(wr * 64 + 32 + nl) * BK + go];
            short8 b0 = *(const short8*)&Bs[cur][(wn * 64 +      nl) * BK + go];
            short8 b1 = *(const short8*)&Bs[cur][(wn * 64 + 32 + nl) * BK + go];
            acc[0] = __builtin_amdgcn_mfma_f32_32x32x16_bf16(a0, b0, acc[0], 0, 0, 0);
            acc[1] = __builtin_amdgcn_mfma_f32_32x32x16_bf16(a0, b1, acc[1], 0, 0, 0);
            acc[2] = __builtin_amdgcn_mfma_f32_32x32x16_bf16(a1, b0, acc[2], 0, 0, 0);
            acc[3] = __builtin_amdgcn_mfma_f32_32x32x16_bf16(a1, b1, acc[3], 0, 0, 0);
        }
        __builtin_amdgcn_s_setprio(0);
        __syncthreads();               // all waves done reading As, Bs[cur]

        if (i + 1 < NT) {
            // stage Bs(i+1) (lands at the trailing sync, under the build)
            const int nxt = cur ^ 1;
            #pragma unroll
            for (int c = 0; c < 4; ++c) { gload_lds16(bg[c], &Bs[nxt][(c * 8 + wave) * 512]); bg[c] += BK; }
            // build As(i+1)
            float4 a0{0,0,0,0}, a1{0,0,0,0}, a2{0,0,0,0}, a3{0,0,0,0},
                   a4{0,0,0,0}, a5{0,0,0,0}, a6{0,0,0,0}, a7{0,0,0,0};
            u64 m = mA;
            while (m) {
                const int j = __builtin_ctzll(m); m &= m - 1;
                const float* hr = &hs[(hb + j) << 6];
                const int key = (hb + j) & 15;
                a0 += *(const float4*)&hr[(((bq * 8 + 0) ^ key) << 2)];
                a1 += *(const float4*)&hr[(((bq * 8 + 1) ^ key) << 2)];
                a2 += *(const float4*)&hr[(((bq * 8 + 2) ^ key) << 2)];
                a3 += *(const float4*)&hr[(((bq * 8 + 3) ^ key) << 2)];
                a4 += *(const float4*)&hr[(((bq * 8 + 4) ^ key) << 2)];
                a5 += *(const float4*)&hr[(((bq * 8 + 5) ^ key) << 2)];
                a6 += *(const float4*)&hr[(((bq * 8 + 6) ^ key) << 2)];
                a7 += *(const float4*)&hr[(((bq * 8 + 7) ^ key) << 2)];
            }
            const int gbase = bc * 8 + bq * 4;
            short8 o;
            o[0]=f2bf(a0.x); o[1]=f2bf(a0.y); o[2]=f2bf(a0.z); o[3]=f2bf(a0.w);
            o[4]=f2bf(a1.x); o[5]=f2bf(a1.y); o[6]=f2bf(a1.z); o[7]=f2bf(a1.w);
            *(short8*)&As[(br << 7) + (((gbase + 0) ^ (br & 15)) << 3)] = o;
            o[0]=f2bf(a2.x); o[1]=f2bf(a2.y); o[2]=f2bf(a2.z); o[3]=f2bf(a2.w);
            o[4]=f2bf(a3.x); o[5]=f2bf(a3.y); o[6]=f2bf(a3.z); o[7]=f2bf(a3.w);
            *(short8*)&As[(br << 7) + (((gbase + 1) ^ (br & 15)) << 3)] = o;
            o[0]=f2bf(a4.x); o[1]=f2bf(a4.y); o[2]=f2bf(a4.z); o[3]=f2bf(a4.w);
            o[4]=f2bf(a5.x); o[5]=f2bf(a5.y); o[6]=f2bf(a5.z); o[7]=f2bf(a5.w);
            *(short8*)&As[(br << 7) + (((gbase + 2) ^ (br & 15)) << 3)] = o;
            o[0]=f2bf(a6.x); o[1]=f2bf(a6.y); o[2]=f2bf(a6.z); o[3]=f2bf(a6.w);
            o[4]=f2bf(a7.x); o[5]=f2bf(a7.y); o[6]=f2bf(a7.z); o[7]=f2bf(a7.w);
            *(short8*)&As[(br << 7) + (((gbase + 3) ^ (br & 15)) << 3)] = o;
        }
        mA = mB;
        __syncthreads();               // As(i+1) visible; Bs(i+1) drained
    }

    // ---- K-half reduction through LDS (reuse Bs, 64 KB), bias+relu+store ----
    // 32x32 C/D layout: col=lane&31, row=(r&3)+8*(r>>2)+4*hl.
    float* red = (float*)Bs;               // [wr*2+wn][64][64] f32 = 64 KB
    if (kh) {
        #pragma unroll
        for (int mi = 0; mi < 2; ++mi)
            #pragma unroll
            for (int ni = 0; ni < 2; ++ni)
                #pragma unroll
                for (int r = 0; r < 16; ++r) {
                    const int row32 = (r & 3) + 8 * (r >> 2) + 4 * hl;
                    red[(wr * 2 + wn) * 4096 + (mi * 32 + row32) * 64 + ni * 32 + nl] =
                        acc[mi * 2 + ni][r];
                }
    }
    __syncthreads();
    if (!kh) {
        const float bv0 = bias[n0 + wn * 64 + nl];
        const float bv1 = bias[n0 + wn * 64 + 32 + nl];
        #pragma unroll
        for (int mi = 0; mi < 2; ++mi)
            #pragma unroll
            for (int ni = 0; ni < 2; ++ni) {
                const float bv = ni ? bv1 : bv0;
                #pragma unroll
                for (int r = 0; r < 16; ++r) {
                    const int row32 = (r & 3) + 8 * (r >> 2) + 4 * hl;
                    const int gm = m0 + wr * 64 + mi * 32 + row32;
                    const int gn = n0 + wn * 64 + ni * 32 + nl;
                    float v = acc[mi * 2 + ni][r]
                            + red[(wr * 2 + wn) * 4096 + (mi * 32 + row32) * 64 + ni * 32 + nl]
                            + bv;
                    out[(size_t)gm * N + gn] = v > 0.f ? v : 0.f;
                }
            }
    }
}

// ---------------------------------------------------------------------------
extern "C" void kernel_launch(void* const* d_in, const int* in_sizes, int n_in,
                              void* d_out, int out_size, void* d_ws, size_t ws_size,
                              hipStream_t stream) {
    const float* h    = (const float*)d_in[0];   // (1, B, 64) f32
    const float* pos  = (const float*)d_in[2];   // (B, 2)     f32
    const float* W    = (const float*)d_in[4];   // (K, N)     f32
    const float* bias = (const float*)d_in[5];   // (N,)       f32

    const int B = in_sizes[0] / 64;       // 4096
    const int N = in_sizes[5];            // 1024
    const int K = 64 * 64;                // GRID^2 * H_DIM = 4096

    u64*   masks = (u64*)d_ws;                       // B*64*8 = 2 MB
    short* Wt    = (short*)(masks + (size_t)B * 64); // N*K bf16 = 8 MB
    float* out   = (float*)d_out;

    const int castBlocks = (K / 64) * (N / 64);      // 1024
    const int maskBlocks = B / 64;                   // 64
    prep2_kernel<<<castBlocks + maskBlocks, 256, 0, stream>>>(
        pos, masks, W, Wt, K, N, castBlocks);
    fused_pool_gemm<<<(B / BM) * (N / BN), 512, 0, stream>>>(
        h, masks, Wt, bias, out, B, N, K);
}